// Round 16
// baseline (244.400 us; speedup 1.0000x reference)
//
#include <hip/hip_runtime.h>
#include <hip/hip_bf16.h>

using bf16s = __hip_bfloat16;
typedef __bf16 bf16x8 __attribute__((ext_vector_type(8)));
typedef float f32x4 __attribute__((ext_vector_type(4)));

constexpr int MS_TILE = 4096;
constexpr int BSH = 8;               // 256-node buckets
constexpr int BN = 256;
constexpr int NBUCK = 512;
constexpr int SLAB_CAP = 5120;       // mean fill 4096, sigma 64 -> 16 sigma slack
constexpr int CSR_CAP = 6912;        // exact worst case: SLAB_CAP + 256*7; mult of 8

__device__ inline float uasf(unsigned u) { return __uint_as_float(u); }

// pack two f32 -> bf16x2 dword (RNE), x low, y high
__device__ inline unsigned pk2(float x, float y) {
    unsigned ux = __float_as_uint(x), uy = __float_as_uint(y);
    ux = (ux + 0x7fffu + ((ux >> 16) & 1u)) >> 16;
    uy = (uy + 0x7fffu + ((uy >> 16) & 1u)) & 0xffff0000u;
    return (ux & 0xffffu) | uy;
}

// ---------------- multisplit: partition edges into 256-node coarse bucket slabs ----
__global__ __launch_bounds__(512) void multisplit(const int* __restrict__ src,
                                                  const int* __restrict__ dst,
                                                  int* __restrict__ gcur,
                                                  int* __restrict__ part, int E) {
    __shared__ int cnt[NBUCK];
    __shared__ int off[NBUCK];
    __shared__ int gbase[NBUCK];
    __shared__ int img[MS_TILE];
    __shared__ int tgt[MS_TILE];
    int tid = threadIdx.x;
    int tbase = blockIdx.x * MS_TILE;
    int m = min(MS_TILE, E - tbase);
    if (tid < NBUCK) cnt[tid] = 0;
    __syncthreads();
    int pk[8], bk[8], rk[8];
    int nloc = 0;
    int j0 = tid * 8;
    if (j0 + 8 <= m) {
        int4 s0 = *(const int4*)(src + tbase + j0);
        int4 s1 = *(const int4*)(src + tbase + j0 + 4);
        int4 d0 = *(const int4*)(dst + tbase + j0);
        int4 d1 = *(const int4*)(dst + tbase + j0 + 4);
        int ss[8] = {s0.x, s0.y, s0.z, s0.w, s1.x, s1.y, s1.z, s1.w};
        int dd[8] = {d0.x, d0.y, d0.z, d0.w, d1.x, d1.y, d1.z, d1.w};
#pragma unroll
        for (int k = 0; k < 8; k++) {
            int b = dd[k] >> BSH;
            pk[k] = (ss[k] << BSH) | (dd[k] & (BN - 1));
            bk[k] = b;
            rk[k] = atomicAdd(&cnt[b], 1);
        }
        nloc = 8;
    } else {
        for (int j = j0; j < m; j++) {
            int s = src[tbase + j], d = dst[tbase + j];
            int b = d >> BSH;
            pk[nloc] = (s << BSH) | (d & (BN - 1));
            bk[nloc] = b;
            rk[nloc] = atomicAdd(&cnt[b], 1);
            nloc++;
        }
    }
    __syncthreads();
    // exclusive scan of cnt[0..512) by wave 0 (64 lanes x 8 serial)
    if (tid < 64) {
        int base = tid * 8;
        int vals[8];
        int s0 = 0;
#pragma unroll
        for (int j = 0; j < 8; j++) { vals[j] = cnt[base + j]; s0 += vals[j]; }
        int sc = s0;
#pragma unroll
        for (int o = 1; o < 64; o <<= 1) {
            int u = __shfl_up(sc, o);
            if (tid >= o) sc += u;
        }
        int ex = sc - s0;
#pragma unroll
        for (int j = 0; j < 8; j++) { off[base + j] = ex; ex += vals[j]; }
    }
    __syncthreads();
    // reserve slab space per bucket (one atomic per WG per nonempty bucket)
    if (tid < NBUCK) {
        int c = cnt[tid];
        if (c) {
            int st = atomicAdd(&gcur[tid], c);
            if (st > SLAB_CAP - c) st = SLAB_CAP - c;   // defensive; never in practice
            gbase[tid] = tid * SLAB_CAP + st;
        }
    }
    __syncthreads();
    // scatter into LDS, grouped by bucket
#pragma unroll
    for (int i = 0; i < 8; i++) {
        if (i < nloc) {
            int p = off[bk[i]] + rk[i];
            img[p] = pk[i];
            tgt[p] = gbase[bk[i]] + rk[i];
        }
    }
    __syncthreads();
    // coalesced write-out (consecutive slots -> consecutive targets per bucket run)
    for (int j = tid; j < m; j += 512) part[tgt[j]] = img[j];
}

// ------- bucket_place: padded per-node CSR + rinfo + dinv from the bucket's slab -----
__global__ __launch_bounds__(512) void bucket_place(const int* __restrict__ gcur,
                                                    const int* __restrict__ part,
                                                    int2* __restrict__ rinfo,
                                                    int* __restrict__ csr,
                                                    float* __restrict__ dinv, int n) {
    __shared__ int cnt[BN];
    __shared__ int cur[BN];
    __shared__ int wtot[4];
    __shared__ int img[CSR_CAP];
    __shared__ int mpad_s;
    int b = blockIdx.x;
    int tid = threadIdx.x;
    int node0 = b << BSH;
    int m = min(gcur[b], SLAB_CAP);
    const int* slab = part + b * SLAB_CAP;
    if (tid < BN) cnt[tid] = 0;
    __syncthreads();
    for (int j = tid; j < m; j += 512) atomicAdd(&cnt[slab[j] & (BN - 1)], 1);
    __syncthreads();
    // wave shfl-scan over 256 padded degrees (waves 0-3)
    int deg = 0, pdeg = 0, ex = 0;
    if (tid < BN) {
        deg = cnt[tid];
        pdeg = (deg + 7) & ~7;
    }
    int lane = tid & 63, wv = tid >> 6;
    if (tid < BN) {
        int sc = pdeg;
#pragma unroll
        for (int o = 1; o < 64; o <<= 1) {
            int u = __shfl_up(sc, o);
            if (lane >= o) sc += u;
        }
        if (lane == 63) wtot[wv] = sc;
        ex = sc - pdeg;
    }
    __syncthreads();
    if (tid < BN) {
        int wbase = 0;
#pragma unroll
        for (int k = 0; k < 4; k++) wbase += (k < wv) ? wtot[k] : 0;
        ex += wbase;
        cur[tid] = ex;
        int node = node0 + tid;
        if (node < n) {
            rinfo[node] = make_int2(b * CSR_CAP + ex, pdeg);
            dinv[node] = rsqrtf((float)(deg + 1));  // +1 = self loop
        }
        int sent = n << 5;          // zero-row dword offset
        for (int j = ex + deg; j < ex + pdeg; j++) img[j] = sent;   // own pad (<=7)
        if (tid == BN - 1) mpad_s = ex + pdeg;
    }
    __syncthreads();
    int mpad = mpad_s;
    for (int j = tid; j < m; j += 512) {
        int pkv = slab[j];
        int p = atomicAdd(&cur[pkv & (BN - 1)], 1);
        img[p] = (pkv >> BSH) << 5;   // dword offset of src row in t
    }
    __syncthreads();
    int* dp = csr + b * CSR_CAP;
    for (int j = tid; j < mpad; j += 512) dp[j] = img[j];   // coalesced
}

// ---- GEMM + dinv prescale: out[r] = bf16(dinv[r] * (A[r] @ W)), MFMA 16x16x32 ----
template <bool AF32>
__global__ __launch_bounds__(256) void gemm64(const void* __restrict__ A_,
                                              const float* __restrict__ W,
                                              const float* __restrict__ dinv,
                                              bf16s* __restrict__ out, int nrows) {
    int lane = threadIdx.x & 63;
    int wid = (blockIdx.x * blockDim.x + threadIdx.x) >> 6;
    int nwaves = (gridDim.x * blockDim.x) >> 6;
    int r = lane & 15;       // col-in-tile
    int q = lane >> 4;       // quad
    int kb = q * 8;

    if (wid == 0) out[(size_t)nrows * 64 + lane] = __float2bfloat16(0.f);  // zero row

    // B fragments: 4 n-tiles x 2 k-halves. B[k][n]: n=lane&15, k=quad*8+j
    bf16x8 bfrag[4][2];
#pragma unroll
    for (int t = 0; t < 4; t++) {
#pragma unroll
        for (int h = 0; h < 2; h++) {
            bf16x8 bb;
            int ncol = t * 16 + r;
            int k0 = h * 32 + kb;
#pragma unroll
            for (int j = 0; j < 8; j++) bb[j] = (__bf16)W[(k0 + j) * 64 + ncol];
            bfrag[t][h] = bb;
        }
    }

    int ntiles = nrows >> 4;
    for (int tile = wid; tile < ntiles; tile += nwaves) {
        bf16x8 a0, a1;
        if (AF32) {
            const float* ap = (const float*)A_ + (size_t)(tile * 16 + r) * 64 + kb;
            f32x4 v0 = *reinterpret_cast<const f32x4*>(ap);
            f32x4 v1 = *reinterpret_cast<const f32x4*>(ap + 4);
            f32x4 v2 = *reinterpret_cast<const f32x4*>(ap + 32);
            f32x4 v3 = *reinterpret_cast<const f32x4*>(ap + 36);
#pragma unroll
            for (int j = 0; j < 4; j++) {
                a0[j] = (__bf16)v0[j]; a0[4 + j] = (__bf16)v1[j];
                a1[j] = (__bf16)v2[j]; a1[4 + j] = (__bf16)v3[j];
            }
        } else {
            const __bf16* ap = (const __bf16*)A_ + (size_t)(tile * 16 + r) * 64 + kb;
            a0 = *reinterpret_cast<const bf16x8*>(ap);
            a1 = *reinterpret_cast<const bf16x8*>(ap + 32);
        }
        f32x4 c[4];
#pragma unroll
        for (int t = 0; t < 4; t++) {
            f32x4 acc = {0.f, 0.f, 0.f, 0.f};
            acc = __builtin_amdgcn_mfma_f32_16x16x32_bf16(a0, bfrag[t][0], acc, 0, 0, 0);
            acc = __builtin_amdgcn_mfma_f32_16x16x32_bf16(a1, bfrag[t][1], acc, 0, 0, 0);
            c[t] = acc;
        }
        // C/D layout: col = lane&15, row = quad*4 + reg
        float dr[4];
#pragma unroll
        for (int g = 0; g < 4; g++) dr[g] = dinv[tile * 16 + q * 4 + g];
#pragma unroll
        for (int t = 0; t < 4; t++) {
#pragma unroll
            for (int g = 0; g < 4; g++) {
                int row = tile * 16 + q * 4 + g;
                out[(size_t)row * 64 + t * 16 + r] = __float2bfloat16(c[t][g] * dr[g]);
            }
        }
    }
}

// ------- aggregate (pull): quarter-wave (16 lanes) per TWO nodes, interleaved -------
template <bool OUTF32>
__global__ __launch_bounds__(256) void aggregate(const unsigned* __restrict__ t32,
                                                 const float* __restrict__ dinv,
                                                 const int2* __restrict__ rinfo,
                                                 const int* __restrict__ csr,
                                                 const float* __restrict__ bias,
                                                 void* __restrict__ out_, int n) {
    int gid = blockIdx.x * blockDim.x + threadIdx.x;
    int qw = gid >> 4;
    int v0 = qw * 2, v1 = v0 + 1;
    if (v0 >= n) return;
    bool has1 = v1 < n;
    int c = gid & 15;
    int2 r0 = rinfo[v0];
    int2 r1 = has1 ? rinfo[v1] : make_int2(0, 0);
    uint2 s0 = *(const uint2*)(t32 + (size_t)v0 * 32 + 2 * c);
    uint2 s1 = has1 ? *(const uint2*)(t32 + (size_t)v1 * 32 + 2 * c) : make_uint2(0, 0);
    float a00 = uasf(s0.x << 16), a01 = uasf(s0.x & 0xffff0000u);
    float a02 = uasf(s0.y << 16), a03 = uasf(s0.y & 0xffff0000u);
    float a10 = uasf(s1.x << 16), a11 = uasf(s1.x & 0xffff0000u);
    float a12 = uasf(s1.y << 16), a13 = uasf(s1.y & 0xffff0000u);
    const int* cp0 = csr + r0.x;
    const int* cp1 = csr + r1.x;
    int j0 = 0, j1 = 0;
    while (j0 < r0.y || j1 < r1.y) {
        bool g0 = j0 < r0.y, g1 = j1 < r1.y;
        int idx0[8], idx1[8];
        uint2 ga[8], gb[8];
        if (g0) {
            int4 e0 = *(const int4*)(cp0 + j0);
            int4 e1 = *(const int4*)(cp0 + j0 + 4);
            idx0[0]=e0.x; idx0[1]=e0.y; idx0[2]=e0.z; idx0[3]=e0.w;
            idx0[4]=e1.x; idx0[5]=e1.y; idx0[6]=e1.z; idx0[7]=e1.w;
#pragma unroll
            for (int k = 0; k < 8; k++)
                ga[k] = *(const uint2*)(t32 + (size_t)idx0[k] + 2 * c);
        }
        if (g1) {
            int4 e0 = *(const int4*)(cp1 + j1);
            int4 e1 = *(const int4*)(cp1 + j1 + 4);
            idx1[0]=e0.x; idx1[1]=e0.y; idx1[2]=e0.z; idx1[3]=e0.w;
            idx1[4]=e1.x; idx1[5]=e1.y; idx1[6]=e1.z; idx1[7]=e1.w;
#pragma unroll
            for (int k = 0; k < 8; k++)
                gb[k] = *(const uint2*)(t32 + (size_t)idx1[k] + 2 * c);
        }
        if (g0) {
#pragma unroll
            for (int k = 0; k < 8; k++) {
                a00 += uasf(ga[k].x << 16);
                a01 += uasf(ga[k].x & 0xffff0000u);
                a02 += uasf(ga[k].y << 16);
                a03 += uasf(ga[k].y & 0xffff0000u);
            }
            j0 += 8;
        }
        if (g1) {
#pragma unroll
            for (int k = 0; k < 8; k++) {
                a10 += uasf(gb[k].x << 16);
                a11 += uasf(gb[k].x & 0xffff0000u);
                a12 += uasf(gb[k].y << 16);
                a13 += uasf(gb[k].y & 0xffff0000u);
            }
            j1 += 8;
        }
    }
    f32x4 bb = ((const f32x4*)bias)[c];
    {
        float dv = dinv[v0];
        float o0 = fmaxf(fmaf(dv, a00, bb[0]), 0.f);
        float o1 = fmaxf(fmaf(dv, a01, bb[1]), 0.f);
        float o2 = fmaxf(fmaf(dv, a02, bb[2]), 0.f);
        float o3 = fmaxf(fmaf(dv, a03, bb[3]), 0.f);
        if (OUTF32) {
            f32x4 o4 = {o0, o1, o2, o3};
            ((f32x4*)out_)[(size_t)v0 * 16 + c] = o4;
        } else {
            uint2 ou; ou.x = pk2(o0, o1); ou.y = pk2(o2, o3);
            ((uint2*)out_)[(size_t)v0 * 16 + c] = ou;
        }
    }
    if (has1) {
        float dv = dinv[v1];
        float o0 = fmaxf(fmaf(dv, a10, bb[0]), 0.f);
        float o1 = fmaxf(fmaf(dv, a11, bb[1]), 0.f);
        float o2 = fmaxf(fmaf(dv, a12, bb[2]), 0.f);
        float o3 = fmaxf(fmaf(dv, a13, bb[3]), 0.f);
        if (OUTF32) {
            f32x4 o4 = {o0, o1, o2, o3};
            ((f32x4*)out_)[(size_t)v1 * 16 + c] = o4;
        } else {
            uint2 ou; ou.x = pk2(o0, o1); ou.y = pk2(o2, o3);
            ((uint2*)out_)[(size_t)v1 * 16 + c] = ou;
        }
    }
}

extern "C" void kernel_launch(void* const* d_in, const int* in_sizes, int n_in,
                              void* d_out, int out_size, void* d_ws, size_t ws_size,
                              hipStream_t stream) {
    const float* x  = (const float*)d_in[0];
    const int*   ei = (const int*)d_in[1];
    const float* W1 = (const float*)d_in[2];
    const float* b1 = (const float*)d_in[3];
    const float* W2 = (const float*)d_in[4];
    const float* b2 = (const float*)d_in[5];
    float* out = (float*)d_out;

    int n = in_sizes[0] / 64;   // 100000
    int E = in_sizes[1] / 2;    // 1600000
    const int* src = ei;
    const int* dst = ei + E;
    int nbuck = (n + BN - 1) >> BSH;   // 391

    // workspace carve
    char* w = (char*)d_ws;
    auto alloc = [&](size_t bytes) -> void* {
        void* p = (void*)w;
        w += (bytes + 255) & ~(size_t)255;
        return p;
    };
    int*   gcur   = (int*)alloc(NBUCK * 4);
    int2*  rinfo  = (int2*)alloc((size_t)n * 8);
    int*   csr    = (int*)alloc((size_t)nbuck * CSR_CAP * 4);   // ~10.8 MB
    float* dinv   = (float*)alloc((size_t)n * 4);
    size_t slab_bytes = (size_t)nbuck * SLAB_CAP * 4;           // 8 MB
    size_t tbuf_bytes = (size_t)(n + 16) * 64 * 2;              // 12.8 MB (+zero row)
    char*  ovl    = (char*)alloc(slab_bytes > tbuf_bytes ? slab_bytes : tbuf_bytes);
    int*   part   = (int*)ovl;
    bf16s* tbuf   = (bf16s*)ovl;
    bf16s* h1     = (bf16s*)alloc((size_t)(n + 16) * 64 * 2);

    int ntiles = (E + MS_TILE - 1) / MS_TILE;   // 391
    // ATTRIBUTION EXPERIMENT (this round only): the pair (memset gcur, multisplit)
    // is idempotent (slab contents set-identical; intra-bucket order noise only
    // permutes fp32 summation order). Run it 4x: delta vs R14 = 3 * pair cost.
    hipMemsetAsync(gcur, 0, NBUCK * 4, stream);
    multisplit<<<ntiles, 512, 0, stream>>>(src, dst, gcur, part, E);
    hipMemsetAsync(gcur, 0, NBUCK * 4, stream);
    multisplit<<<ntiles, 512, 0, stream>>>(src, dst, gcur, part, E);
    hipMemsetAsync(gcur, 0, NBUCK * 4, stream);
    multisplit<<<ntiles, 512, 0, stream>>>(src, dst, gcur, part, E);
    hipMemsetAsync(gcur, 0, NBUCK * 4, stream);
    multisplit<<<ntiles, 512, 0, stream>>>(src, dst, gcur, part, E);

    bucket_place<<<nbuck, 512, 0, stream>>>(gcur, part, rinfo, csr, dinv, n);

    int agrid = (n * 8 + 255) / 256;   // 3125
    // layer 1: t = bf16(dinv .* (x @ W1)); h1 = relu(aggregate) in bf16
    gemm64<true><<<1024, 256, 0, stream>>>(x, W1, dinv, tbuf, n);
    aggregate<false><<<agrid, 256, 0, stream>>>((const unsigned*)tbuf, dinv, rinfo, csr, b1, h1, n);
    // layer 2: t = bf16(dinv .* (h1 @ W2)); out = relu(aggregate) in fp32
    gemm64<false><<<1024, 256, 0, stream>>>(h1, W2, dinv, tbuf, n);
    aggregate<true><<<agrid, 256, 0, stream>>>((const unsigned*)tbuf, dinv, rinfo, csr, b2, out, n);
}

// Round 17
// 214.522 us; speedup vs baseline: 1.1393x; 1.1393x over previous
//
#include <hip/hip_runtime.h>
#include <hip/hip_bf16.h>

using bf16s = __hip_bfloat16;
typedef __bf16 bf16x8 __attribute__((ext_vector_type(8)));
typedef float f32x4 __attribute__((ext_vector_type(4)));

constexpr int MS_TILE = 4096;
constexpr int BSH = 8;               // 256-node buckets
constexpr int BN = 256;
constexpr int NBUCK = 512;
constexpr int SLAB_CAP = 5120;       // mean fill 4096, sigma 64 -> 16 sigma slack
constexpr int CSR_CAP = 6912;        // exact worst case: SLAB_CAP + 256*7; mult of 8

__device__ inline float uasf(unsigned u) { return __uint_as_float(u); }

// pack two f32 -> bf16x2 dword (RNE), x low, y high
__device__ inline unsigned pk2(float x, float y) {
    unsigned ux = __float_as_uint(x), uy = __float_as_uint(y);
    ux = (ux + 0x7fffu + ((ux >> 16) & 1u)) >> 16;
    uy = (uy + 0x7fffu + ((uy >> 16) & 1u)) & 0xffff0000u;
    return (ux & 0xffffu) | uy;
}

// ---------------- multisplit: partition edges into 256-node coarse bucket slabs ----
__global__ __launch_bounds__(512) void multisplit(const int* __restrict__ src,
                                                  const int* __restrict__ dst,
                                                  int* __restrict__ gcur,
                                                  int* __restrict__ part, int E) {
    __shared__ int cnt[NBUCK];
    __shared__ int off[NBUCK];
    __shared__ int gbase[NBUCK];
    __shared__ int img[MS_TILE];
    __shared__ int tgt[MS_TILE];
    int tid = threadIdx.x;
    int tbase = blockIdx.x * MS_TILE;
    int m = min(MS_TILE, E - tbase);
    if (tid < NBUCK) cnt[tid] = 0;
    __syncthreads();
    int pk[8], bk[8], rk[8];
    int nloc = 0;
    int j0 = tid * 8;
    if (j0 + 8 <= m) {
        int4 s0 = *(const int4*)(src + tbase + j0);
        int4 s1 = *(const int4*)(src + tbase + j0 + 4);
        int4 d0 = *(const int4*)(dst + tbase + j0);
        int4 d1 = *(const int4*)(dst + tbase + j0 + 4);
        int ss[8] = {s0.x, s0.y, s0.z, s0.w, s1.x, s1.y, s1.z, s1.w};
        int dd[8] = {d0.x, d0.y, d0.z, d0.w, d1.x, d1.y, d1.z, d1.w};
#pragma unroll
        for (int k = 0; k < 8; k++) {
            int b = dd[k] >> BSH;
            pk[k] = (ss[k] << BSH) | (dd[k] & (BN - 1));
            bk[k] = b;
            rk[k] = atomicAdd(&cnt[b], 1);
        }
        nloc = 8;
    } else {
        for (int j = j0; j < m; j++) {
            int s = src[tbase + j], d = dst[tbase + j];
            int b = d >> BSH;
            pk[nloc] = (s << BSH) | (d & (BN - 1));
            bk[nloc] = b;
            rk[nloc] = atomicAdd(&cnt[b], 1);
            nloc++;
        }
    }
    __syncthreads();
    // exclusive scan of cnt[0..512) by wave 0 (64 lanes x 8 serial)
    if (tid < 64) {
        int base = tid * 8;
        int vals[8];
        int s0 = 0;
#pragma unroll
        for (int j = 0; j < 8; j++) { vals[j] = cnt[base + j]; s0 += vals[j]; }
        int sc = s0;
#pragma unroll
        for (int o = 1; o < 64; o <<= 1) {
            int u = __shfl_up(sc, o);
            if (tid >= o) sc += u;
        }
        int ex = sc - s0;
#pragma unroll
        for (int j = 0; j < 8; j++) { off[base + j] = ex; ex += vals[j]; }
    }
    __syncthreads();
    // reserve slab space per bucket (one atomic per WG per nonempty bucket)
    if (tid < NBUCK) {
        int c = cnt[tid];
        if (c) {
            int st = atomicAdd(&gcur[tid], c);
            if (st > SLAB_CAP - c) st = SLAB_CAP - c;   // defensive; never in practice
            gbase[tid] = tid * SLAB_CAP + st;
        }
    }
    __syncthreads();
    // scatter into LDS, grouped by bucket
#pragma unroll
    for (int i = 0; i < 8; i++) {
        if (i < nloc) {
            int p = off[bk[i]] + rk[i];
            img[p] = pk[i];
            tgt[p] = gbase[bk[i]] + rk[i];
        }
    }
    __syncthreads();
    // coalesced write-out (consecutive slots -> consecutive targets per bucket run)
    for (int j = tid; j < m; j += 512) part[tgt[j]] = img[j];
}

// ------- bucket_place: padded per-node CSR + rinfo + dinv from the bucket's slab -----
__global__ __launch_bounds__(512) void bucket_place(const int* __restrict__ gcur,
                                                    const int* __restrict__ part,
                                                    int2* __restrict__ rinfo,
                                                    int* __restrict__ csr,
                                                    float* __restrict__ dinv, int n) {
    __shared__ int cnt[BN];
    __shared__ int cur[BN];
    __shared__ int wtot[4];
    __shared__ int img[CSR_CAP];
    __shared__ int mpad_s;
    int b = blockIdx.x;
    int tid = threadIdx.x;
    int node0 = b << BSH;
    int m = min(gcur[b], SLAB_CAP);
    const int* slab = part + b * SLAB_CAP;
    if (tid < BN) cnt[tid] = 0;
    __syncthreads();
    for (int j = tid; j < m; j += 512) atomicAdd(&cnt[slab[j] & (BN - 1)], 1);
    __syncthreads();
    // wave shfl-scan over 256 padded degrees (waves 0-3)
    int deg = 0, pdeg = 0, ex = 0;
    if (tid < BN) {
        deg = cnt[tid];
        pdeg = (deg + 7) & ~7;
    }
    int lane = tid & 63, wv = tid >> 6;
    if (tid < BN) {
        int sc = pdeg;
#pragma unroll
        for (int o = 1; o < 64; o <<= 1) {
            int u = __shfl_up(sc, o);
            if (lane >= o) sc += u;
        }
        if (lane == 63) wtot[wv] = sc;
        ex = sc - pdeg;
    }
    __syncthreads();
    if (tid < BN) {
        int wbase = 0;
#pragma unroll
        for (int k = 0; k < 4; k++) wbase += (k < wv) ? wtot[k] : 0;
        ex += wbase;
        cur[tid] = ex;
        int node = node0 + tid;
        if (node < n) {
            rinfo[node] = make_int2(b * CSR_CAP + ex, pdeg);
            dinv[node] = rsqrtf((float)(deg + 1));  // +1 = self loop
        }
        int sent = n << 5;          // zero-row dword offset
        for (int j = ex + deg; j < ex + pdeg; j++) img[j] = sent;   // own pad (<=7)
        if (tid == BN - 1) mpad_s = ex + pdeg;
    }
    __syncthreads();
    int mpad = mpad_s;
    for (int j = tid; j < m; j += 512) {
        int pkv = slab[j];
        int p = atomicAdd(&cur[pkv & (BN - 1)], 1);
        img[p] = (pkv >> BSH) << 5;   // dword offset of src row in t
    }
    __syncthreads();
    int* dp = csr + b * CSR_CAP;
    for (int j = tid; j < mpad; j += 512) dp[j] = img[j];   // coalesced
}

// ---- GEMM + dinv prescale: out[r] = bf16(dinv[r] * (A[r] @ W)), MFMA 16x16x32 ----
template <bool AF32>
__global__ __launch_bounds__(256) void gemm64(const void* __restrict__ A_,
                                              const float* __restrict__ W,
                                              const float* __restrict__ dinv,
                                              bf16s* __restrict__ out, int nrows) {
    int lane = threadIdx.x & 63;
    int wid = (blockIdx.x * blockDim.x + threadIdx.x) >> 6;
    int nwaves = (gridDim.x * blockDim.x) >> 6;
    int r = lane & 15;       // col-in-tile
    int q = lane >> 4;       // quad
    int kb = q * 8;

    if (wid == 0) out[(size_t)nrows * 64 + lane] = __float2bfloat16(0.f);  // zero row

    // B fragments: 4 n-tiles x 2 k-halves. B[k][n]: n=lane&15, k=quad*8+j
    bf16x8 bfrag[4][2];
#pragma unroll
    for (int t = 0; t < 4; t++) {
#pragma unroll
        for (int h = 0; h < 2; h++) {
            bf16x8 bb;
            int ncol = t * 16 + r;
            int k0 = h * 32 + kb;
#pragma unroll
            for (int j = 0; j < 8; j++) bb[j] = (__bf16)W[(k0 + j) * 64 + ncol];
            bfrag[t][h] = bb;
        }
    }

    int ntiles = nrows >> 4;
    for (int tile = wid; tile < ntiles; tile += nwaves) {
        bf16x8 a0, a1;
        if (AF32) {
            const float* ap = (const float*)A_ + (size_t)(tile * 16 + r) * 64 + kb;
            f32x4 v0 = *reinterpret_cast<const f32x4*>(ap);
            f32x4 v1 = *reinterpret_cast<const f32x4*>(ap + 4);
            f32x4 v2 = *reinterpret_cast<const f32x4*>(ap + 32);
            f32x4 v3 = *reinterpret_cast<const f32x4*>(ap + 36);
#pragma unroll
            for (int j = 0; j < 4; j++) {
                a0[j] = (__bf16)v0[j]; a0[4 + j] = (__bf16)v1[j];
                a1[j] = (__bf16)v2[j]; a1[4 + j] = (__bf16)v3[j];
            }
        } else {
            const __bf16* ap = (const __bf16*)A_ + (size_t)(tile * 16 + r) * 64 + kb;
            a0 = *reinterpret_cast<const bf16x8*>(ap);
            a1 = *reinterpret_cast<const bf16x8*>(ap + 32);
        }
        f32x4 c[4];
#pragma unroll
        for (int t = 0; t < 4; t++) {
            f32x4 acc = {0.f, 0.f, 0.f, 0.f};
            acc = __builtin_amdgcn_mfma_f32_16x16x32_bf16(a0, bfrag[t][0], acc, 0, 0, 0);
            acc = __builtin_amdgcn_mfma_f32_16x16x32_bf16(a1, bfrag[t][1], acc, 0, 0, 0);
            c[t] = acc;
        }
        // C/D layout: col = lane&15, row = quad*4 + reg
        float dr[4];
#pragma unroll
        for (int g = 0; g < 4; g++) dr[g] = dinv[tile * 16 + q * 4 + g];
#pragma unroll
        for (int t = 0; t < 4; t++) {
#pragma unroll
            for (int g = 0; g < 4; g++) {
                int row = tile * 16 + q * 4 + g;
                out[(size_t)row * 64 + t * 16 + r] = __float2bfloat16(c[t][g] * dr[g]);
            }
        }
    }
}

// ------- aggregate (pull): quarter-wave (16 lanes) per TWO nodes, interleaved -------
template <bool OUTF32>
__global__ __launch_bounds__(256) void aggregate(const unsigned* __restrict__ t32,
                                                 const float* __restrict__ dinv,
                                                 const int2* __restrict__ rinfo,
                                                 const int* __restrict__ csr,
                                                 const float* __restrict__ bias,
                                                 void* __restrict__ out_, int n) {
    int gid = blockIdx.x * blockDim.x + threadIdx.x;
    int qw = gid >> 4;
    int v0 = qw * 2, v1 = v0 + 1;
    if (v0 >= n) return;
    bool has1 = v1 < n;
    int c = gid & 15;
    int2 r0 = rinfo[v0];
    int2 r1 = has1 ? rinfo[v1] : make_int2(0, 0);
    uint2 s0 = *(const uint2*)(t32 + (size_t)v0 * 32 + 2 * c);
    uint2 s1 = has1 ? *(const uint2*)(t32 + (size_t)v1 * 32 + 2 * c) : make_uint2(0, 0);
    float a00 = uasf(s0.x << 16), a01 = uasf(s0.x & 0xffff0000u);
    float a02 = uasf(s0.y << 16), a03 = uasf(s0.y & 0xffff0000u);
    float a10 = uasf(s1.x << 16), a11 = uasf(s1.x & 0xffff0000u);
    float a12 = uasf(s1.y << 16), a13 = uasf(s1.y & 0xffff0000u);
    const int* cp0 = csr + r0.x;
    const int* cp1 = csr + r1.x;
    int j0 = 0, j1 = 0;
    while (j0 < r0.y || j1 < r1.y) {
        bool g0 = j0 < r0.y, g1 = j1 < r1.y;
        int idx0[8], idx1[8];
        uint2 ga[8], gb[8];
        if (g0) {
            int4 e0 = *(const int4*)(cp0 + j0);
            int4 e1 = *(const int4*)(cp0 + j0 + 4);
            idx0[0]=e0.x; idx0[1]=e0.y; idx0[2]=e0.z; idx0[3]=e0.w;
            idx0[4]=e1.x; idx0[5]=e1.y; idx0[6]=e1.z; idx0[7]=e1.w;
#pragma unroll
            for (int k = 0; k < 8; k++)
                ga[k] = *(const uint2*)(t32 + (size_t)idx0[k] + 2 * c);
        }
        if (g1) {
            int4 e0 = *(const int4*)(cp1 + j1);
            int4 e1 = *(const int4*)(cp1 + j1 + 4);
            idx1[0]=e0.x; idx1[1]=e0.y; idx1[2]=e0.z; idx1[3]=e0.w;
            idx1[4]=e1.x; idx1[5]=e1.y; idx1[6]=e1.z; idx1[7]=e1.w;
#pragma unroll
            for (int k = 0; k < 8; k++)
                gb[k] = *(const uint2*)(t32 + (size_t)idx1[k] + 2 * c);
        }
        if (g0) {
#pragma unroll
            for (int k = 0; k < 8; k++) {
                a00 += uasf(ga[k].x << 16);
                a01 += uasf(ga[k].x & 0xffff0000u);
                a02 += uasf(ga[k].y << 16);
                a03 += uasf(ga[k].y & 0xffff0000u);
            }
            j0 += 8;
        }
        if (g1) {
#pragma unroll
            for (int k = 0; k < 8; k++) {
                a10 += uasf(gb[k].x << 16);
                a11 += uasf(gb[k].x & 0xffff0000u);
                a12 += uasf(gb[k].y << 16);
                a13 += uasf(gb[k].y & 0xffff0000u);
            }
            j1 += 8;
        }
    }
    f32x4 bb = ((const f32x4*)bias)[c];
    {
        float dv = dinv[v0];
        float o0 = fmaxf(fmaf(dv, a00, bb[0]), 0.f);
        float o1 = fmaxf(fmaf(dv, a01, bb[1]), 0.f);
        float o2 = fmaxf(fmaf(dv, a02, bb[2]), 0.f);
        float o3 = fmaxf(fmaf(dv, a03, bb[3]), 0.f);
        if (OUTF32) {
            f32x4 o4 = {o0, o1, o2, o3};
            ((f32x4*)out_)[(size_t)v0 * 16 + c] = o4;
        } else {
            uint2 ou; ou.x = pk2(o0, o1); ou.y = pk2(o2, o3);
            ((uint2*)out_)[(size_t)v0 * 16 + c] = ou;
        }
    }
    if (has1) {
        float dv = dinv[v1];
        float o0 = fmaxf(fmaf(dv, a10, bb[0]), 0.f);
        float o1 = fmaxf(fmaf(dv, a11, bb[1]), 0.f);
        float o2 = fmaxf(fmaf(dv, a12, bb[2]), 0.f);
        float o3 = fmaxf(fmaf(dv, a13, bb[3]), 0.f);
        if (OUTF32) {
            f32x4 o4 = {o0, o1, o2, o3};
            ((f32x4*)out_)[(size_t)v1 * 16 + c] = o4;
        } else {
            uint2 ou; ou.x = pk2(o0, o1); ou.y = pk2(o2, o3);
            ((uint2*)out_)[(size_t)v1 * 16 + c] = ou;
        }
    }
}

extern "C" void kernel_launch(void* const* d_in, const int* in_sizes, int n_in,
                              void* d_out, int out_size, void* d_ws, size_t ws_size,
                              hipStream_t stream) {
    const float* x  = (const float*)d_in[0];
    const int*   ei = (const int*)d_in[1];
    const float* W1 = (const float*)d_in[2];
    const float* b1 = (const float*)d_in[3];
    const float* W2 = (const float*)d_in[4];
    const float* b2 = (const float*)d_in[5];
    float* out = (float*)d_out;

    int n = in_sizes[0] / 64;   // 100000
    int E = in_sizes[1] / 2;    // 1600000
    const int* src = ei;
    const int* dst = ei + E;
    int nbuck = (n + BN - 1) >> BSH;   // 391

    // workspace carve
    char* w = (char*)d_ws;
    auto alloc = [&](size_t bytes) -> void* {
        void* p = (void*)w;
        w += (bytes + 255) & ~(size_t)255;
        return p;
    };
    int*   gcur   = (int*)alloc(NBUCK * 4);
    int2*  rinfo  = (int2*)alloc((size_t)n * 8);
    int*   csr    = (int*)alloc((size_t)nbuck * CSR_CAP * 4);   // ~10.8 MB
    float* dinv   = (float*)alloc((size_t)n * 4);
    size_t slab_bytes = (size_t)nbuck * SLAB_CAP * 4;           // 8 MB
    size_t tbuf_bytes = (size_t)(n + 16) * 64 * 2;              // 12.8 MB (+zero row)
    char*  ovl    = (char*)alloc(slab_bytes > tbuf_bytes ? slab_bytes : tbuf_bytes);
    int*   part   = (int*)ovl;
    bf16s* tbuf   = (bf16s*)ovl;
    bf16s* h1     = (bf16s*)alloc((size_t)(n + 16) * 64 * 2);

    hipMemsetAsync(gcur, 0, NBUCK * 4, stream);

    int ntiles = (E + MS_TILE - 1) / MS_TILE;   // 391
    multisplit<<<ntiles, 512, 0, stream>>>(src, dst, gcur, part, E);
    bucket_place<<<nbuck, 512, 0, stream>>>(gcur, part, rinfo, csr, dinv, n);

    int agrid = (n * 8 + 255) / 256;   // 3125
    // ATTRIBUTION EXPERIMENT (this round only): gemm64 is idempotent; run each 2x.
    // Delta vs R14 = 2 * (dur(gemm64) + kernel-boundary cost).
    gemm64<true><<<1024, 256, 0, stream>>>(x, W1, dinv, tbuf, n);
    gemm64<true><<<1024, 256, 0, stream>>>(x, W1, dinv, tbuf, n);
    aggregate<false><<<agrid, 256, 0, stream>>>((const unsigned*)tbuf, dinv, rinfo, csr, b1, h1, n);
    gemm64<false><<<1024, 256, 0, stream>>>(h1, W2, dinv, tbuf, n);
    gemm64<false><<<1024, 256, 0, stream>>>(h1, W2, dinv, tbuf, n);
    aggregate<true><<<agrid, 256, 0, stream>>>((const unsigned*)tbuf, dinv, rinfo, csr, b2, out, n);
}

// Round 18
// 198.753 us; speedup vs baseline: 1.2297x; 1.0793x over previous
//
#include <hip/hip_runtime.h>
#include <hip/hip_bf16.h>

using bf16s = __hip_bfloat16;
typedef __bf16 bf16x8 __attribute__((ext_vector_type(8)));
typedef float f32x4 __attribute__((ext_vector_type(4)));

constexpr int MS_TILE = 4096;
constexpr int BSH = 8;               // 256-node buckets
constexpr int BN = 256;
constexpr int NBUCK = 512;
constexpr int SLAB_CAP = 5120;       // mean fill 4096, sigma 64 -> 16 sigma slack
constexpr int CSR_CAP = 6912;        // exact worst case: SLAB_CAP + 256*7; mult of 8

__device__ inline float uasf(unsigned u) { return __uint_as_float(u); }

// pack two f32 -> bf16x2 dword (RNE), x low, y high
__device__ inline unsigned pk2(float x, float y) {
    unsigned ux = __float_as_uint(x), uy = __float_as_uint(y);
    ux = (ux + 0x7fffu + ((ux >> 16) & 1u)) >> 16;
    uy = (uy + 0x7fffu + ((uy >> 16) & 1u)) & 0xffff0000u;
    return (ux & 0xffffu) | uy;
}

// ---------------- multisplit: partition edges into 256-node coarse bucket slabs ----
__global__ __launch_bounds__(512) void multisplit(const int* __restrict__ src,
                                                  const int* __restrict__ dst,
                                                  int* __restrict__ gcur,
                                                  int* __restrict__ part, int E) {
    __shared__ int cnt[NBUCK];
    __shared__ int off[NBUCK];
    __shared__ int gbase[NBUCK];
    __shared__ int img[MS_TILE];
    __shared__ int tgt[MS_TILE];
    int tid = threadIdx.x;
    int tbase = blockIdx.x * MS_TILE;
    int m = min(MS_TILE, E - tbase);
    if (tid < NBUCK) cnt[tid] = 0;
    __syncthreads();
    int pk[8], bk[8], rk[8];
    int nloc = 0;
    int j0 = tid * 8;
    if (j0 + 8 <= m) {
        int4 s0 = *(const int4*)(src + tbase + j0);
        int4 s1 = *(const int4*)(src + tbase + j0 + 4);
        int4 d0 = *(const int4*)(dst + tbase + j0);
        int4 d1 = *(const int4*)(dst + tbase + j0 + 4);
        int ss[8] = {s0.x, s0.y, s0.z, s0.w, s1.x, s1.y, s1.z, s1.w};
        int dd[8] = {d0.x, d0.y, d0.z, d0.w, d1.x, d1.y, d1.z, d1.w};
#pragma unroll
        for (int k = 0; k < 8; k++) {
            int b = dd[k] >> BSH;
            pk[k] = (ss[k] << BSH) | (dd[k] & (BN - 1));
            bk[k] = b;
            rk[k] = atomicAdd(&cnt[b], 1);
        }
        nloc = 8;
    } else {
        for (int j = j0; j < m; j++) {
            int s = src[tbase + j], d = dst[tbase + j];
            int b = d >> BSH;
            pk[nloc] = (s << BSH) | (d & (BN - 1));
            bk[nloc] = b;
            rk[nloc] = atomicAdd(&cnt[b], 1);
            nloc++;
        }
    }
    __syncthreads();
    // exclusive scan of cnt[0..512) by wave 0 (64 lanes x 8 serial)
    if (tid < 64) {
        int base = tid * 8;
        int vals[8];
        int s0 = 0;
#pragma unroll
        for (int j = 0; j < 8; j++) { vals[j] = cnt[base + j]; s0 += vals[j]; }
        int sc = s0;
#pragma unroll
        for (int o = 1; o < 64; o <<= 1) {
            int u = __shfl_up(sc, o);
            if (tid >= o) sc += u;
        }
        int ex = sc - s0;
#pragma unroll
        for (int j = 0; j < 8; j++) { off[base + j] = ex; ex += vals[j]; }
    }
    __syncthreads();
    // reserve slab space per bucket (one atomic per WG per nonempty bucket)
    if (tid < NBUCK) {
        int c = cnt[tid];
        if (c) {
            int st = atomicAdd(&gcur[tid], c);
            if (st > SLAB_CAP - c) st = SLAB_CAP - c;   // defensive; never in practice
            gbase[tid] = tid * SLAB_CAP + st;
        }
    }
    __syncthreads();
    // scatter into LDS, grouped by bucket
#pragma unroll
    for (int i = 0; i < 8; i++) {
        if (i < nloc) {
            int p = off[bk[i]] + rk[i];
            img[p] = pk[i];
            tgt[p] = gbase[bk[i]] + rk[i];
        }
    }
    __syncthreads();
    // coalesced write-out (consecutive slots -> consecutive targets per bucket run)
    for (int j = tid; j < m; j += 512) part[tgt[j]] = img[j];
}

// ------- bucket_place: padded per-node CSR + rinfo + dinv from the bucket's slab -----
__global__ __launch_bounds__(512) void bucket_place(const int* __restrict__ gcur,
                                                    const int* __restrict__ part,
                                                    int2* __restrict__ rinfo,
                                                    int* __restrict__ csr,
                                                    float* __restrict__ dinv, int n) {
    __shared__ int cnt[BN];
    __shared__ int cur[BN];
    __shared__ int wtot[4];
    __shared__ int img[CSR_CAP];
    __shared__ int mpad_s;
    int b = blockIdx.x;
    int tid = threadIdx.x;
    int node0 = b << BSH;
    int m = min(gcur[b], SLAB_CAP);
    const int* slab = part + b * SLAB_CAP;
    if (tid < BN) cnt[tid] = 0;
    __syncthreads();
    for (int j = tid; j < m; j += 512) atomicAdd(&cnt[slab[j] & (BN - 1)], 1);
    __syncthreads();
    // wave shfl-scan over 256 padded degrees (waves 0-3)
    int deg = 0, pdeg = 0, ex = 0;
    if (tid < BN) {
        deg = cnt[tid];
        pdeg = (deg + 7) & ~7;
    }
    int lane = tid & 63, wv = tid >> 6;
    if (tid < BN) {
        int sc = pdeg;
#pragma unroll
        for (int o = 1; o < 64; o <<= 1) {
            int u = __shfl_up(sc, o);
            if (lane >= o) sc += u;
        }
        if (lane == 63) wtot[wv] = sc;
        ex = sc - pdeg;
    }
    __syncthreads();
    if (tid < BN) {
        int wbase = 0;
#pragma unroll
        for (int k = 0; k < 4; k++) wbase += (k < wv) ? wtot[k] : 0;
        ex += wbase;
        cur[tid] = ex;
        int node = node0 + tid;
        if (node < n) {
            rinfo[node] = make_int2(b * CSR_CAP + ex, pdeg);
            dinv[node] = rsqrtf((float)(deg + 1));  // +1 = self loop
        }
        int sent = n << 5;          // zero-row dword offset
        for (int j = ex + deg; j < ex + pdeg; j++) img[j] = sent;   // own pad (<=7)
        if (tid == BN - 1) mpad_s = ex + pdeg;
    }
    __syncthreads();
    int mpad = mpad_s;
    for (int j = tid; j < m; j += 512) {
        int pkv = slab[j];
        int p = atomicAdd(&cur[pkv & (BN - 1)], 1);
        img[p] = (pkv >> BSH) << 5;   // dword offset of src row in t
    }
    __syncthreads();
    int* dp = csr + b * CSR_CAP;
    for (int j = tid; j < mpad; j += 512) dp[j] = img[j];   // coalesced
}

// ---- GEMM + dinv prescale: out[r] = bf16(dinv[r] * (A[r] @ W)), MFMA 16x16x32 ----
template <bool AF32>
__global__ __launch_bounds__(256) void gemm64(const void* __restrict__ A_,
                                              const float* __restrict__ W,
                                              const float* __restrict__ dinv,
                                              bf16s* __restrict__ out, int nrows) {
    int lane = threadIdx.x & 63;
    int wid = (blockIdx.x * blockDim.x + threadIdx.x) >> 6;
    int nwaves = (gridDim.x * blockDim.x) >> 6;
    int r = lane & 15;       // col-in-tile
    int q = lane >> 4;       // quad
    int kb = q * 8;

    if (wid == 0) out[(size_t)nrows * 64 + lane] = __float2bfloat16(0.f);  // zero row

    // B fragments: 4 n-tiles x 2 k-halves. B[k][n]: n=lane&15, k=quad*8+j
    bf16x8 bfrag[4][2];
#pragma unroll
    for (int t = 0; t < 4; t++) {
#pragma unroll
        for (int h = 0; h < 2; h++) {
            bf16x8 bb;
            int ncol = t * 16 + r;
            int k0 = h * 32 + kb;
#pragma unroll
            for (int j = 0; j < 8; j++) bb[j] = (__bf16)W[(k0 + j) * 64 + ncol];
            bfrag[t][h] = bb;
        }
    }

    int ntiles = nrows >> 4;
    for (int tile = wid; tile < ntiles; tile += nwaves) {
        bf16x8 a0, a1;
        if (AF32) {
            const float* ap = (const float*)A_ + (size_t)(tile * 16 + r) * 64 + kb;
            f32x4 v0 = *reinterpret_cast<const f32x4*>(ap);
            f32x4 v1 = *reinterpret_cast<const f32x4*>(ap + 4);
            f32x4 v2 = *reinterpret_cast<const f32x4*>(ap + 32);
            f32x4 v3 = *reinterpret_cast<const f32x4*>(ap + 36);
#pragma unroll
            for (int j = 0; j < 4; j++) {
                a0[j] = (__bf16)v0[j]; a0[4 + j] = (__bf16)v1[j];
                a1[j] = (__bf16)v2[j]; a1[4 + j] = (__bf16)v3[j];
            }
        } else {
            const __bf16* ap = (const __bf16*)A_ + (size_t)(tile * 16 + r) * 64 + kb;
            a0 = *reinterpret_cast<const bf16x8*>(ap);
            a1 = *reinterpret_cast<const bf16x8*>(ap + 32);
        }
        f32x4 c[4];
#pragma unroll
        for (int t = 0; t < 4; t++) {
            f32x4 acc = {0.f, 0.f, 0.f, 0.f};
            acc = __builtin_amdgcn_mfma_f32_16x16x32_bf16(a0, bfrag[t][0], acc, 0, 0, 0);
            acc = __builtin_amdgcn_mfma_f32_16x16x32_bf16(a1, bfrag[t][1], acc, 0, 0, 0);
            c[t] = acc;
        }
        // C/D layout: col = lane&15, row = quad*4 + reg
        float dr[4];
#pragma unroll
        for (int g = 0; g < 4; g++) dr[g] = dinv[tile * 16 + q * 4 + g];
#pragma unroll
        for (int t = 0; t < 4; t++) {
#pragma unroll
            for (int g = 0; g < 4; g++) {
                int row = tile * 16 + q * 4 + g;
                out[(size_t)row * 64 + t * 16 + r] = __float2bfloat16(c[t][g] * dr[g]);
            }
        }
    }
}

// ------- aggregate (pull): quarter-wave (16 lanes) per TWO nodes, interleaved -------
template <bool OUTF32>
__global__ __launch_bounds__(256) void aggregate(const unsigned* __restrict__ t32,
                                                 const float* __restrict__ dinv,
                                                 const int2* __restrict__ rinfo,
                                                 const int* __restrict__ csr,
                                                 const float* __restrict__ bias,
                                                 void* __restrict__ out_, int n) {
    int gid = blockIdx.x * blockDim.x + threadIdx.x;
    int qw = gid >> 4;
    int v0 = qw * 2, v1 = v0 + 1;
    if (v0 >= n) return;
    bool has1 = v1 < n;
    int c = gid & 15;
    int2 r0 = rinfo[v0];
    int2 r1 = has1 ? rinfo[v1] : make_int2(0, 0);
    uint2 s0 = *(const uint2*)(t32 + (size_t)v0 * 32 + 2 * c);
    uint2 s1 = has1 ? *(const uint2*)(t32 + (size_t)v1 * 32 + 2 * c) : make_uint2(0, 0);
    float a00 = uasf(s0.x << 16), a01 = uasf(s0.x & 0xffff0000u);
    float a02 = uasf(s0.y << 16), a03 = uasf(s0.y & 0xffff0000u);
    float a10 = uasf(s1.x << 16), a11 = uasf(s1.x & 0xffff0000u);
    float a12 = uasf(s1.y << 16), a13 = uasf(s1.y & 0xffff0000u);
    const int* cp0 = csr + r0.x;
    const int* cp1 = csr + r1.x;
    int j0 = 0, j1 = 0;
    while (j0 < r0.y || j1 < r1.y) {
        bool g0 = j0 < r0.y, g1 = j1 < r1.y;
        int idx0[8], idx1[8];
        uint2 ga[8], gb[8];
        if (g0) {
            int4 e0 = *(const int4*)(cp0 + j0);
            int4 e1 = *(const int4*)(cp0 + j0 + 4);
            idx0[0]=e0.x; idx0[1]=e0.y; idx0[2]=e0.z; idx0[3]=e0.w;
            idx0[4]=e1.x; idx0[5]=e1.y; idx0[6]=e1.z; idx0[7]=e1.w;
#pragma unroll
            for (int k = 0; k < 8; k++)
                ga[k] = *(const uint2*)(t32 + (size_t)idx0[k] + 2 * c);
        }
        if (g1) {
            int4 e0 = *(const int4*)(cp1 + j1);
            int4 e1 = *(const int4*)(cp1 + j1 + 4);
            idx1[0]=e0.x; idx1[1]=e0.y; idx1[2]=e0.z; idx1[3]=e0.w;
            idx1[4]=e1.x; idx1[5]=e1.y; idx1[6]=e1.z; idx1[7]=e1.w;
#pragma unroll
            for (int k = 0; k < 8; k++)
                gb[k] = *(const uint2*)(t32 + (size_t)idx1[k] + 2 * c);
        }
        if (g0) {
#pragma unroll
            for (int k = 0; k < 8; k++) {
                a00 += uasf(ga[k].x << 16);
                a01 += uasf(ga[k].x & 0xffff0000u);
                a02 += uasf(ga[k].y << 16);
                a03 += uasf(ga[k].y & 0xffff0000u);
            }
            j0 += 8;
        }
        if (g1) {
#pragma unroll
            for (int k = 0; k < 8; k++) {
                a10 += uasf(gb[k].x << 16);
                a11 += uasf(gb[k].x & 0xffff0000u);
                a12 += uasf(gb[k].y << 16);
                a13 += uasf(gb[k].y & 0xffff0000u);
            }
            j1 += 8;
        }
    }
    f32x4 bb = ((const f32x4*)bias)[c];
    {
        float dv = dinv[v0];
        float o0 = fmaxf(fmaf(dv, a00, bb[0]), 0.f);
        float o1 = fmaxf(fmaf(dv, a01, bb[1]), 0.f);
        float o2 = fmaxf(fmaf(dv, a02, bb[2]), 0.f);
        float o3 = fmaxf(fmaf(dv, a03, bb[3]), 0.f);
        if (OUTF32) {
            f32x4 o4 = {o0, o1, o2, o3};
            ((f32x4*)out_)[(size_t)v0 * 16 + c] = o4;
        } else {
            uint2 ou; ou.x = pk2(o0, o1); ou.y = pk2(o2, o3);
            ((uint2*)out_)[(size_t)v0 * 16 + c] = ou;
        }
    }
    if (has1) {
        float dv = dinv[v1];
        float o0 = fmaxf(fmaf(dv, a10, bb[0]), 0.f);
        float o1 = fmaxf(fmaf(dv, a11, bb[1]), 0.f);
        float o2 = fmaxf(fmaf(dv, a12, bb[2]), 0.f);
        float o3 = fmaxf(fmaf(dv, a13, bb[3]), 0.f);
        if (OUTF32) {
            f32x4 o4 = {o0, o1, o2, o3};
            ((f32x4*)out_)[(size_t)v1 * 16 + c] = o4;
        } else {
            uint2 ou; ou.x = pk2(o0, o1); ou.y = pk2(o2, o3);
            ((uint2*)out_)[(size_t)v1 * 16 + c] = ou;
        }
    }
}

extern "C" void kernel_launch(void* const* d_in, const int* in_sizes, int n_in,
                              void* d_out, int out_size, void* d_ws, size_t ws_size,
                              hipStream_t stream) {
    const float* x  = (const float*)d_in[0];
    const int*   ei = (const int*)d_in[1];
    const float* W1 = (const float*)d_in[2];
    const float* b1 = (const float*)d_in[3];
    const float* W2 = (const float*)d_in[4];
    const float* b2 = (const float*)d_in[5];
    float* out = (float*)d_out;

    int n = in_sizes[0] / 64;   // 100000
    int E = in_sizes[1] / 2;    // 1600000
    const int* src = ei;
    const int* dst = ei + E;
    int nbuck = (n + BN - 1) >> BSH;   // 391

    // workspace carve
    char* w = (char*)d_ws;
    auto alloc = [&](size_t bytes) -> void* {
        void* p = (void*)w;
        w += (bytes + 255) & ~(size_t)255;
        return p;
    };
    int*   gcur   = (int*)alloc(NBUCK * 4);
    int2*  rinfo  = (int2*)alloc((size_t)n * 8);
    int*   csr    = (int*)alloc((size_t)nbuck * CSR_CAP * 4);   // ~10.8 MB
    float* dinv   = (float*)alloc((size_t)n * 4);
    size_t slab_bytes = (size_t)nbuck * SLAB_CAP * 4;           // 8 MB
    size_t tbuf_bytes = (size_t)(n + 16) * 64 * 2;              // 12.8 MB (+zero row)
    char*  ovl    = (char*)alloc(slab_bytes > tbuf_bytes ? slab_bytes : tbuf_bytes);
    int*   part   = (int*)ovl;
    bf16s* tbuf   = (bf16s*)ovl;
    bf16s* h1     = (bf16s*)alloc((size_t)(n + 16) * 64 * 2);

    hipMemsetAsync(gcur, 0, NBUCK * 4, stream);

    int ntiles = (E + MS_TILE - 1) / MS_TILE;   // 391
    multisplit<<<ntiles, 512, 0, stream>>>(src, dst, gcur, part, E);
    bucket_place<<<nbuck, 512, 0, stream>>>(gcur, part, rinfo, csr, dinv, n);

    int agrid = (n * 8 + 255) / 256;   // 3125
    // layer 1: t = bf16(dinv .* (x @ W1)); h1 = relu(aggregate) in bf16
    gemm64<true><<<1024, 256, 0, stream>>>(x, W1, dinv, tbuf, n);
    aggregate<false><<<agrid, 256, 0, stream>>>((const unsigned*)tbuf, dinv, rinfo, csr, b1, h1, n);
    // layer 2: t = bf16(dinv .* (h1 @ W2)); out = relu(aggregate) in fp32
    gemm64<false><<<1024, 256, 0, stream>>>(h1, W2, dinv, tbuf, n);
    aggregate<true><<<agrid, 256, 0, stream>>>((const unsigned*)tbuf, dinv, rinfo, csr, b2, out, n);
}